// Round 7
// baseline (1319.404 us; speedup 1.0000x reference)
//
#include <hip/hip_runtime.h>

// Problem constants
constexpr int D  = 128;
constexpr int M  = 8192;
constexpr int L  = 5;
constexpr int K  = 8;
constexpr int KL = 4;
constexpr int G  = 4096;

constexpr int TB   = 64;            // bucket pad granularity == row tile
constexpr int PADL = M + K * TB;    // 8704 -> 136 row-tiles of 64
constexpr int PADG = G + KL * TB;   // 4352 -> 68 row-tiles of 64
constexpr int SLOTS = 32;           // max row-tiles per bucket (stat. safe: mean 16, sigma<1)

typedef short bf16x8 __attribute__((ext_vector_type(8)));
typedef float f32x4  __attribute__((ext_vector_type(4)));

__device__ __forceinline__ unsigned short f2bf(float x) {
  union { float f; unsigned int u; } c; c.f = x;
  unsigned int u = c.u + 0x7FFF + ((c.u >> 16) & 1);   // RNE
  return (unsigned short)(u >> 16);
}
__device__ __forceinline__ float bf2f(unsigned short h) {
  union { unsigned int u; float f; } c; c.u = ((unsigned int)h) << 16;
  return c.f;
}

// ---------------------------------------------------------------------------
__global__ void leaf_gather_kernel(const int* __restrict__ leaf_ids,
                                   const float* __restrict__ emb,
                                   float* __restrict__ h0) {
  int idx = blockIdx.x * 256 + threadIdx.x;
  int n = idx >> 7, d = idx & 127;
  h0[idx] = emb[(size_t)leaf_ids[n] * D + d];
}

// out = o0 + o1 (final split-K reduction for logic layer 2)
__global__ void add_out_kernel(const float* __restrict__ o0,
                               const float* __restrict__ o1,
                               float* __restrict__ out) {
  int idx = blockIdx.x * 256 + threadIdx.x;
  out[idx] = o0[idx] + o1[idx];
}

// ---------------------------------------------------------------------------
// Bucket node indices by fid, padded to 64; pad = -1. Valid entries are a
// prefix of each bucket, so every 64-row tile is fid-uniform. Also emits a
// per-bucket tile schedule: sched[k*SLOTS+s] = row-tile index or -1.
__global__ void bucket64_kernel(const int* __restrict__ nf_fid,
                                const int* __restrict__ lf_fid,
                                int* __restrict__ orders,
                                int* __restrict__ schedL,
                                int* __restrict__ schedG) {
  int b = blockIdx.x;
  const int* fid; int N, Kf, cap; int* out; int* sch;
  if (b < L) { fid = nf_fid + b * M; N = M; Kf = K;  cap = PADL; out = orders + b * PADL; sch = schedL + b * K * SLOTS; }
  else       { fid = lf_fid;         N = G; Kf = KL; cap = PADG; out = orders + L * PADL; sch = schedG; }
  __shared__ int cnt[8];
  __shared__ int cur[8];
  __shared__ int tbS[8], tcS[8];
  int tid = threadIdx.x;
  if (tid < Kf) cnt[tid] = 0;
  __syncthreads();
  for (int i = tid; i < N; i += 256) atomicAdd(&cnt[fid[i]], 1);
  __syncthreads();
  if (tid == 0) {
    int off = 0;
    for (int k = 0; k < Kf; ++k) {
      int tiles = (cnt[k] + TB - 1) / TB;
      tbS[k] = off / TB; tcS[k] = tiles;
      cur[k] = off; off += tiles * TB;
    }
  }
  __syncthreads();
  for (int i = tid; i < cap; i += 256) out[i] = -1;
  // schedule table
  for (int i = tid; i < Kf * SLOTS; i += 256) {
    int k = i / SLOTS, s = i % SLOTS;
    sch[i] = (s < tcS[k]) ? (tbS[k] + s) : -1;
  }
  __syncthreads();
  for (int i = tid; i < N; i += 256) {
    int kk = fid[i];
    int pos = atomicAdd(&cur[kk], 1);
    out[pos] = i;
  }
}

// ---------------------------------------------------------------------------
// Weight prep: W[k][KD][F] fp32 -> BT[k][F][2*KD] bf16 as [hi(KD) | lo(KD)].
__global__ void prep_kernel(const float* __restrict__ W1, const float* __restrict__ W2,
                            const float* __restrict__ W3, const float* __restrict__ Wl1,
                            const float* __restrict__ Wl2,
                            short* __restrict__ B1T, short* __restrict__ B2T,
                            short* __restrict__ B3T, short* __restrict__ BL1T,
                            short* __restrict__ BL2T) {
  int b = blockIdx.x;
  const float* W; short* BT; int KD, F;
  if      (b < 4096) { W = W1;  BT = B1T;  KD = 256; F = 512; }
  else if (b < 6144) { W = W2;  BT = B2T;  KD = 512; F = 256; b -= 4096; }
  else if (b < 7168) { W = W3;  BT = B3T;  KD = 256; F = 128; b -= 6144; }
  else if (b < 9216) { W = Wl1; BT = BL1T; KD = 256; F = 512; b -= 7168; }
  else               { W = Wl2; BT = BL2T; KD = 512; F = 128; b -= 9216; }
  int k = b / F, f = b % F;
  for (int d = threadIdx.x; d < KD; d += 256) {
    float w = W[((size_t)k * KD + d) * F + f];
    unsigned short hi = f2bf(w);
    unsigned short lo = f2bf(w - bf2f(hi));
    BT[((size_t)k * F + f) * (2 * KD) + d]      = (short)hi;
    BT[((size_t)k * F + f) * (2 * KD) + KD + d] = (short)lo;
  }
}

// ---------------------------------------------------------------------------
// Gather + split: xs[r][0:256]=hi(concat(h[gl],h[gr])), xs[r][256:512]=lo.
// SUMIN=1: input h is a split-K partial pair h0,h1 (summed here).
template<int SUMIN>
__global__ __launch_bounds__(256) void gather_split_kernel(
    const float* __restrict__ h0, const float* __restrict__ h1,
    const int* __restrict__ order,
    const int* __restrict__ gl, const int* __restrict__ gr,
    short* __restrict__ xs) {
  const int r = blockIdx.x * 32 + (threadIdx.x >> 3);
  const int d0 = (threadIdx.x & 7) * 32;
  const int node = order[r];
  float v[32];
  if (node >= 0) {
    const int src = (d0 < 128) ? gl[node] : gr[node];
    const int dd = (d0 < 128) ? d0 : d0 - 128;
    const float4* p0 = (const float4*)(h0 + (size_t)src * 128 + dd);
    #pragma unroll
    for (int i = 0; i < 8; ++i) ((float4*)v)[i] = p0[i];
    if (SUMIN) {
      const float4* p1 = (const float4*)(h1 + (size_t)src * 128 + dd);
      #pragma unroll
      for (int i = 0; i < 8; ++i) {
        float4 w = p1[i];
        v[4 * i + 0] += w.x; v[4 * i + 1] += w.y;
        v[4 * i + 2] += w.z; v[4 * i + 3] += w.w;
      }
    }
  } else {
    #pragma unroll
    for (int i = 0; i < 32; ++i) v[i] = 0.f;
  }
  union { unsigned short u[32]; int4 q[4]; } hi, lo;
  #pragma unroll
  for (int i = 0; i < 32; ++i) {
    unsigned short hh = f2bf(v[i]);
    hi.u[i] = hh;
    lo.u[i] = f2bf(v[i] - bf2f(hh));
  }
  int4* dh = (int4*)&xs[(size_t)r * 512 + d0];
  int4* dl = (int4*)&xs[(size_t)r * 512 + 256 + d0];
  #pragma unroll
  for (int i = 0; i < 4; ++i) { dh[i] = hi.q[i]; dl[i] = lo.q[i]; }
}

// ---------------------------------------------------------------------------
// Grouped GEMM, split-bf16 (logical K' = 3*KH over phys layout [hi|lo]):
//   A' segs {0,1,2} -> phys {hi, lo, hi};  B' segs -> {hi, hi, lo}
// XCD-pinned scheduling: blockIdx.x decodes (xcd -> bucket k, ct, slot) with
// ct fastest among same-XCD ids; sched[k*SLOTS+slot] gives the row-tile.
// KB=8 (levels): k = xcd. KB=4 (logic): k = xcd>>1, slot interleaves parity.
// Block: 256 thr, 64 rows x TC cols; BK=128, depth-2 register prefetch.
// NZ>1: blockIdx.z selects a K'-slice (split-K, EPI==1); consumer sums.
// EPI=0: relu(acc+bias) -> split hi/lo bf16 to Aout (coalesced via LDS).
// EPI=1: acc (+bias iff z==0) -> fp32 scatter to outp + z*partStride.
template<int KH, int NN, int TC, int EPI, int NZ, int KB, int CT>
__global__ __launch_bounds__(256) void mfma_gemm(
    const short* __restrict__ A, const short* __restrict__ BT,
    const float* __restrict__ bias,
    short* __restrict__ Aout, float* __restrict__ outp, size_t partStride,
    const int* __restrict__ order, const int* __restrict__ fid,
    const int* __restrict__ sched) {
  constexpr int BK  = 128;
  constexpr int NCH = 3 * KH / BK;          // 6 (KH=256) or 12 (KH=512)
  static_assert(NCH % NZ == 0, "split must divide chunks");
  constexpr int CN  = NCH / NZ;
  constexpr int LDA = BK + 8;               // 136 shorts -> 2-way bank alias (free)
  constexpr int CF  = TC / 32;              // col frags per wave (2 or 4)
  constexpr int SPB = TC * BK / 256;        // B staging shorts/thread (32 or 64)
  constexpr int TPB = BK / SPB;             // B staging threads/col (4 or 2)
  __shared__ __align__(16) short As[64 * LDA];
  __shared__ __align__(16) short Bs[TC * LDA];
  __shared__ int nodesS[64];

  const int tid = threadIdx.x;
  // ---- XCD-pinned block decode
  const int id = blockIdx.x;
  const int xcd = id & 7;
  const int rest = id >> 3;
  const int ct = rest % CT;
  const int sidx = rest / CT;
  int kb, slot;
  if (KB == 8) { kb = xcd; slot = sidx; }
  else         { kb = xcd >> 1; slot = sidx * 2 + (xcd & 1); }
  const int rt = sched[kb * SLOTS + slot];
  if (rt < 0) return;
  const int row0 = rt * 64;
  const int z = blockIdx.z;

  if (tid < 64) nodesS[tid] = order[row0 + tid];
  __syncthreads();
  if (nodesS[0] < 0) return;
  const int kfn = fid[nodesS[0]];
  const short* __restrict__ Bk = BT + (size_t)kfn * NN * (2 * KH);

  const int lane = tid & 63, wave = tid >> 6;
  const int l15 = lane & 15, oct = lane >> 4;
  const int wr  = (wave >> 1) * 32;
  const int wcg = (wave & 1) * (TC / 2);

  const int ar = tid >> 2;                  // A staging: 64 rows x 4 thr
  const int ag = (tid & 3) * 32;            // 32 shorts (4 int4)
  const int bcol = tid / TPB;               // B staging col
  const int bg = (tid % TPB) * SPB;

  const int c0 = z * CN;

  f32x4 acc[2][CF];
  #pragma unroll
  for (int i = 0; i < 2; ++i)
    #pragma unroll
    for (int j = 0; j < CF; ++j) acc[i][j] = (f32x4)0.f;

  int4 Areg[2][4];
  int4 Breg[2][SPB / 8];

  auto loadA = [&](int set, int c) {
    int ko = c * BK, seg = ko / KH, wi = ko % KH;
    int pa = (seg == 1) ? KH + wi : wi;
    const int4* p = (const int4*)(A + (size_t)(row0 + ar) * (2 * KH) + pa + ag);
    #pragma unroll
    for (int q = 0; q < 4; ++q) Areg[set][q] = p[q];
  };
  auto loadB = [&](int set, int c) {
    int ko = c * BK, seg = ko / KH, wi = ko % KH;
    int pb = (seg == 2) ? KH + wi : wi;
    const int4* p = (const int4*)(Bk + (size_t)(ct * TC + bcol) * (2 * KH) + pb + bg);
    #pragma unroll
    for (int q = 0; q < SPB / 8; ++q) Breg[set][q] = p[q];
  };
  auto storeLDS = [&](int set) {
    int4* da = (int4*)&As[ar * LDA + ag];
    #pragma unroll
    for (int q = 0; q < 4; ++q) da[q] = Areg[set][q];
    int4* db = (int4*)&Bs[bcol * LDA + bg];
    #pragma unroll
    for (int q = 0; q < SPB / 8; ++q) db[q] = Breg[set][q];
  };
  auto compute = [&]() {
    #pragma unroll
    for (int ss = 0; ss < BK / 32; ++ss) {
      const int ko = ss * 32 + oct * 8;
      bf16x8 a0 = *(const bf16x8*)&As[(wr + l15) * LDA + ko];
      bf16x8 a1 = *(const bf16x8*)&As[(wr + 16 + l15) * LDA + ko];
      #pragma unroll
      for (int cf = 0; cf < CF; ++cf) {
        bf16x8 b = *(const bf16x8*)&Bs[(wcg + cf * 16 + l15) * LDA + ko];
        acc[0][cf] = __builtin_amdgcn_mfma_f32_16x16x32_bf16(a0, b, acc[0][cf], 0, 0, 0);
        acc[1][cf] = __builtin_amdgcn_mfma_f32_16x16x32_bf16(a1, b, acc[1][cf], 0, 0, 0);
      }
    }
  };

  loadA(0, c0); loadB(0, c0);
  if (CN > 1) { loadA(1, c0 + 1); loadB(1, c0 + 1); }
  for (int c = 0; c < CN; ++c) {
    const int s = c & 1;
    __syncthreads();
    storeLDS(s);
    __syncthreads();
    if (c + 2 < CN) { loadA(s, c0 + c + 2); loadB(s, c0 + c + 2); }
    compute();
  }

  // ---- Epilogue (coalesced via LDS reuse of Bs)
  // C/D layout: col = l15, row = oct*4 + j (m89-verified).
  if (EPI == 0) {
    short* Ls = (short*)Bs;
    #pragma unroll
    for (int part = 0; part < 2; ++part) {
      __syncthreads();
      #pragma unroll
      for (int rf = 0; rf < 2; ++rf)
        #pragma unroll
        for (int cf = 0; cf < CF; ++cf) {
          int colL = wcg + cf * 16 + l15;
          float bv = bias[kfn * NN + ct * TC + colL];
          #pragma unroll
          for (int j = 0; j < 4; ++j) {
            int row = wr + rf * 16 + oct * 4 + j;
            float v = fmaxf(acc[rf][cf][j] + bv, 0.f);
            unsigned short hh = f2bf(v);
            unsigned short val = (part == 0) ? hh : f2bf(v - bf2f(hh));
            Ls[row * TC + colL] = (short)val;
          }
        }
      __syncthreads();
      constexpr int SPT = TC / 4;
      int row = tid >> 2, sg = (tid & 3) * SPT;
      const int4* src = (const int4*)&Ls[row * TC + sg];
      int4* dst = (int4*)&Aout[(size_t)(row0 + row) * (2 * NN) + part * NN + ct * TC + sg];
      #pragma unroll
      for (int q = 0; q < SPT / 8; ++q) dst[q] = src[q];
    }
  } else {
    float* Lf = (float*)Bs;
    __syncthreads();
    #pragma unroll
    for (int rf = 0; rf < 2; ++rf)
      #pragma unroll
      for (int cf = 0; cf < CF; ++cf) {
        int colL = wcg + cf * 16 + l15;
        float bv = (z == 0) ? bias[kfn * NN + ct * TC + colL] : 0.f;
        #pragma unroll
        for (int j = 0; j < 4; ++j) {
          int row = wr + rf * 16 + oct * 4 + j;
          Lf[row * TC + colL] = acc[rf][cf][j] + bv;
        }
      }
    __syncthreads();
    float* outz = outp + (size_t)z * partStride;
    constexpr int FPT = TC / 4;
    int row = tid >> 2, fo = (tid & 3) * FPT;
    int node = nodesS[row];
    if (node >= 0) {
      const float4* src = (const float4*)&Lf[row * TC + fo];
      float4* dst = (float4*)&outz[(size_t)node * NN + ct * TC + fo];
      #pragma unroll
      for (int q = 0; q < FPT / 4; ++q) dst[q] = src[q];
    }
  }
}

// ---------------------------------------------------------------------------
extern "C" void kernel_launch(void* const* d_in, const int* in_sizes, int n_in,
                              void* d_out, int out_size, void* d_ws, size_t ws_size,
                              hipStream_t stream) {
  const int*   leaf_ids  = (const int*)d_in[0];
  const int*   left_idx  = (const int*)d_in[1];
  const int*   right_idx = (const int*)d_in[2];
  const int*   nf_fid    = (const int*)d_in[3];
  const int*   gt_left   = (const int*)d_in[4];
  const int*   gt_right  = (const int*)d_in[5];
  const int*   lf_fid    = (const int*)d_in[6];
  const float* emb       = (const float*)d_in[7];
  const float* W1 = (const float*)d_in[8];
  const float* b1 = (const float*)d_in[9];
  const float* W2 = (const float*)d_in[10];
  const float* b2 = (const float*)d_in[11];
  const float* W3 = (const float*)d_in[12];
  const float* b3 = (const float*)d_in[13];
  const float* Wl1 = (const float*)d_in[14];
  const float* bl1 = (const float*)d_in[15];
  const float* Wl2 = (const float*)d_in[16];
  const float* bl2 = (const float*)d_in[17];
  float* out = (float*)d_out;

  const size_t SZ_H    = (size_t)M * D * 4;
  const size_t SZ_O    = (size_t)G * D * 4;
  const size_t SZ_XS   = (size_t)PADL * 512 * 2;
  const size_t SZ_A1   = (size_t)PADL * 1024 * 2;
  const size_t SZ_A2   = (size_t)PADL * 512 * 2;
  const size_t SZ_B1T  = (size_t)8 * 512 * 512 * 2;
  const size_t SZ_B2T  = (size_t)8 * 256 * 1024 * 2;
  const size_t SZ_B3T  = (size_t)8 * 128 * 512 * 2;
  const size_t SZ_BL1T = (size_t)4 * 512 * 512 * 2;
  const size_t SZ_BL2T = (size_t)4 * 128 * 1024 * 2;
  const size_t SZ_ORD  = (size_t)(5 * PADL + PADG) * 4;

  char* p = (char*)d_ws;
  float* hA  = (float*)p;  p += SZ_H;
  float* p0  = (float*)p;  p += SZ_H;   // partial pair A (contiguous)
  float* p1  = (float*)p;  p += SZ_H;
  float* q0  = (float*)p;  p += SZ_H;   // partial pair B (contiguous)
  float* q1  = (float*)p;  p += SZ_H;
  float* o0  = (float*)p;  p += SZ_O;   // logic2 partials (contiguous)
  float* o1  = (float*)p;  p += SZ_O;
  short* xsb = (short*)p;  p += SZ_XS;
  short* a1s = (short*)p;  p += SZ_A1;
  short* a2s = (short*)p;  p += SZ_A2;
  short* B1T  = (short*)p; p += SZ_B1T;
  short* B2T  = (short*)p; p += SZ_B2T;
  short* B3T  = (short*)p; p += SZ_B3T;
  short* BL1T = (short*)p; p += SZ_BL1T;
  short* BL2T = (short*)p; p += SZ_BL2T;
  int*   orders = (int*)p; p += SZ_ORD;
  int*   schedL = (int*)p; p += (size_t)L * K * SLOTS * 4;
  int*   schedG = (int*)p;

  leaf_gather_kernel<<<(M * D) / 256, 256, 0, stream>>>(leaf_ids, emb, hA);
  bucket64_kernel<<<L + 1, 256, 0, stream>>>(nf_fid, lf_fid, orders, schedL, schedG);
  prep_kernel<<<9728, 256, 0, stream>>>(W1, W2, W3, Wl1, Wl2,
                                        B1T, B2T, B3T, BL1T, BL2T);

  const size_t HSTRIDE = (size_t)M * D;
  float* in0 = hA; float* in1 = nullptr;
  float* ou0 = q0;
  for (int l = 0; l < L; ++l) {
    const int* ord = orders + l * PADL;
    const int* fidl = nf_fid + l * M;
    const int* schl = schedL + l * K * SLOTS;
    if (l == 0) {
      gather_split_kernel<0><<<PADL / 32, 256, 0, stream>>>(
          in0, nullptr, ord, left_idx, right_idx, xsb);
    } else {
      gather_split_kernel<1><<<PADL / 32, 256, 0, stream>>>(
          in0, in1, ord, left_idx + l * M, right_idx + l * M, xsb);
    }
    // GEMM1: K'=768, N=512, TC=128, CT=4 -> grid 8*4*32 = 1024 (544 useful)
    mfma_gemm<256, 512, 128, 0, 1, 8, 4><<<dim3(8 * 4 * SLOTS, 1, 1), 256, 0, stream>>>(
        xsb, B1T, b1, a1s, nullptr, 0, ord, fidl, schl);
    // GEMM2: K'=1536, N=256, TC=64, CT=4 -> grid 1024 (544 useful)
    mfma_gemm<512, 256, 64, 0, 1, 8, 4><<<dim3(8 * 4 * SLOTS, 1, 1), 256, 0, stream>>>(
        a1s, B2T, b2, a2s, nullptr, 0, ord, fidl, schl);
    // GEMM3: K'=768, N=128, TC=64, CT=2, split-K 2 -> grid (512,1,2)
    mfma_gemm<256, 128, 64, 1, 2, 8, 2><<<dim3(8 * 2 * SLOTS, 1, 2), 256, 0, stream>>>(
        a2s, B3T, b3, nullptr, ou0, HSTRIDE, ord, fidl, schl);
    in0 = ou0; in1 = ou0 + HSTRIDE;
    ou0 = (ou0 == q0) ? p0 : q0;
  }
  const int* ordG = orders + L * PADL;
  gather_split_kernel<1><<<PADG / 32, 256, 0, stream>>>(
      in0, in1, ordG, gt_left, gt_right, xsb);
  // Logic GEMM1: K'=768, N=512, TC=64, CT=8, KB=4 -> grid 8*8*16 = 1024 (544 useful)
  mfma_gemm<256, 512, 64, 0, 1, 4, 8><<<dim3(8 * 8 * (SLOTS / 2), 1, 1), 256, 0, stream>>>(
      xsb, BL1T, bl1, a1s, nullptr, 0, ordG, lf_fid, schedG);
  // Logic GEMM2: K'=1536, N=128, TC=64, CT=2, KB=4, split-K 2 -> grid (256,1,2)
  mfma_gemm<512, 128, 64, 1, 2, 4, 2><<<dim3(8 * 2 * (SLOTS / 2), 1, 2), 256, 0, stream>>>(
      a1s, BL2T, bl2, nullptr, o0, (size_t)G * D, ordG, lf_fid, schedG);
  add_out_kernel<<<(G * D) / 256, 256, 0, stream>>>(o0, o1, out);
}

// Round 8
// 1112.927 us; speedup vs baseline: 1.1855x; 1.1855x over previous
//
#include <hip/hip_runtime.h>

// Problem constants
constexpr int D  = 128;
constexpr int M  = 8192;
constexpr int L  = 5;
constexpr int K  = 8;
constexpr int KL = 4;
constexpr int G  = 4096;

constexpr int TB   = 128;           // bucket pad granularity == row tile
constexpr int PADL = M + K * TB;    // 9216 -> 72 row-tiles of 128
constexpr int PADG = G + KL * TB;   // 4608 -> 36 row-tiles of 128
constexpr int NPHASE = 17;          // 5 levels x 3 GEMMs + 2 logic GEMMs

typedef short bf16x8 __attribute__((ext_vector_type(8)));
typedef float f32x4  __attribute__((ext_vector_type(4)));

__device__ __forceinline__ unsigned short f2bf(float x) {
  union { float f; unsigned int u; } c; c.f = x;
  unsigned int u = c.u + 0x7FFF + ((c.u >> 16) & 1);   // RNE
  return (unsigned short)(u >> 16);
}
__device__ __forceinline__ float bf2f(unsigned short h) {
  union { unsigned int u; float f; } c; c.u = ((unsigned int)h) << 16;
  return c.f;
}

// ---------------------------------------------------------------------------
__global__ void leaf_gather_kernel(const int* __restrict__ leaf_ids,
                                   const float* __restrict__ emb,
                                   float* __restrict__ h0) {
  int idx = blockIdx.x * 256 + threadIdx.x;
  int n = idx >> 7, d = idx & 127;
  h0[idx] = emb[(size_t)leaf_ids[n] * D + d];
}

// out = o0+o1+o2+o3 (split-K=4 reduction for logic layer 2)
__global__ void add_out4_kernel(const float* __restrict__ o, size_t stride,
                                float* __restrict__ out) {
  int idx = blockIdx.x * 256 + threadIdx.x;
  out[idx] = o[idx] + o[idx + stride] + o[idx + 2 * stride] + o[idx + 3 * stride];
}

// ---------------------------------------------------------------------------
// Bucket nodes by fid, padded to 128; pad = -1 (valid rows are a prefix of
// each bucket). Emits per-set meta[8][2] = {tileBase, tileCnt} and zeroes the
// per-phase work-queue counters.
__global__ void bucket128_kernel(const int* __restrict__ nf_fid,
                                 const int* __restrict__ lf_fid,
                                 int* __restrict__ orders,
                                 int* __restrict__ meta,   // [6][8][2]
                                 int* __restrict__ ctrs) { // [NPHASE][8]
  int b = blockIdx.x;
  const int* fid; int N, Kf, cap; int* out; int* mt;
  if (b < L) { fid = nf_fid + b * M; N = M; Kf = K;  cap = PADL; out = orders + b * PADL; mt = meta + b * 16; }
  else       { fid = lf_fid;         N = G; Kf = KL; cap = PADG; out = orders + L * PADL; mt = meta + L * 16; }
  __shared__ int cnt[8];
  __shared__ int cur[8];
  int tid = threadIdx.x;
  if (tid < 8) cnt[tid] = 0;
  __syncthreads();
  for (int i = tid; i < N; i += 256) atomicAdd(&cnt[fid[i]], 1);
  __syncthreads();
  if (tid == 0) {
    int off = 0;
    for (int k = 0; k < Kf; ++k) {
      int tiles = (cnt[k] + TB - 1) / TB;
      mt[2 * k] = off / TB; mt[2 * k + 1] = tiles;
      cur[k] = off; off += tiles * TB;
    }
    for (int k = Kf; k < 8; ++k) { mt[2 * k] = 0; mt[2 * k + 1] = 0; }
  }
  __syncthreads();
  for (int i = tid; i < cap; i += 256) out[i] = -1;
  if (b == 0) for (int i = tid; i < NPHASE * 8; i += 256) ctrs[i] = 0;
  __syncthreads();
  for (int i = tid; i < N; i += 256) {
    int kk = fid[i];
    int pos = atomicAdd(&cur[kk], 1);
    out[pos] = i;
  }
}

// ---------------------------------------------------------------------------
// Weight prep: W[k][KD][F] fp32 -> BT[k][F][2*KD] bf16 as [hi(KD) | lo(KD)].
__global__ void prep_kernel(const float* __restrict__ W1, const float* __restrict__ W2,
                            const float* __restrict__ W3, const float* __restrict__ Wl1,
                            const float* __restrict__ Wl2,
                            short* __restrict__ B1T, short* __restrict__ B2T,
                            short* __restrict__ B3T, short* __restrict__ BL1T,
                            short* __restrict__ BL2T) {
  int b = blockIdx.x;
  const float* W; short* BT; int KD, F;
  if      (b < 4096) { W = W1;  BT = B1T;  KD = 256; F = 512; }
  else if (b < 6144) { W = W2;  BT = B2T;  KD = 512; F = 256; b -= 4096; }
  else if (b < 7168) { W = W3;  BT = B3T;  KD = 256; F = 128; b -= 6144; }
  else if (b < 9216) { W = Wl1; BT = BL1T; KD = 256; F = 512; b -= 7168; }
  else               { W = Wl2; BT = BL2T; KD = 512; F = 128; b -= 9216; }
  int k = b / F, f = b % F;
  for (int d = threadIdx.x; d < KD; d += 256) {
    float w = W[((size_t)k * KD + d) * F + f];
    unsigned short hi = f2bf(w);
    unsigned short lo = f2bf(w - bf2f(hi));
    BT[((size_t)k * F + f) * (2 * KD) + d]      = (short)hi;
    BT[((size_t)k * F + f) * (2 * KD) + KD + d] = (short)lo;
  }
}

// ---------------------------------------------------------------------------
// Gather + split: xs[r][0:256]=hi(concat(h[gl],h[gr])), xs[r][256:512]=lo.
// SUMIN=1: input is a split-K partial pair (h0, h0+partStride), summed here.
template<int SUMIN>
__global__ __launch_bounds__(256) void gather_split_kernel(
    const float* __restrict__ h0, size_t partStride,
    const int* __restrict__ order,
    const int* __restrict__ gl, const int* __restrict__ gr,
    short* __restrict__ xs) {
  const int r = blockIdx.x * 32 + (threadIdx.x >> 3);
  const int d0 = (threadIdx.x & 7) * 32;
  const int node = order[r];
  float v[32];
  if (node >= 0) {
    const int src = (d0 < 128) ? gl[node] : gr[node];
    const int dd = (d0 < 128) ? d0 : d0 - 128;
    const float4* p0 = (const float4*)(h0 + (size_t)src * 128 + dd);
    #pragma unroll
    for (int i = 0; i < 8; ++i) ((float4*)v)[i] = p0[i];
    if (SUMIN) {
      const float4* p1 = (const float4*)(h0 + partStride + (size_t)src * 128 + dd);
      #pragma unroll
      for (int i = 0; i < 8; ++i) {
        float4 w = p1[i];
        v[4 * i + 0] += w.x; v[4 * i + 1] += w.y;
        v[4 * i + 2] += w.z; v[4 * i + 3] += w.w;
      }
    }
  } else {
    #pragma unroll
    for (int i = 0; i < 32; ++i) v[i] = 0.f;
  }
  union { unsigned short u[32]; int4 q[4]; } hi, lo;
  #pragma unroll
  for (int i = 0; i < 32; ++i) {
    unsigned short hh = f2bf(v[i]);
    hi.u[i] = hh;
    lo.u[i] = f2bf(v[i] - bf2f(hh));
  }
  int4* dh = (int4*)&xs[(size_t)r * 512 + d0];
  int4* dl = (int4*)&xs[(size_t)r * 512 + 256 + d0];
  #pragma unroll
  for (int i = 0; i < 4; ++i) { dh[i] = hi.q[i]; dl[i] = lo.q[i]; }
}

// ---------------------------------------------------------------------------
// Grouped GEMM, split-bf16 (logical K' = 3*KH over phys [hi|lo]):
//   A' segs {0,1,2} -> phys {hi, lo, hi};  B' segs -> {hi, hi, lo}
// 128 rows x 128 cols per block (256 thr, 4 waves 2x2, wave tile 64x64,
// acc 4x4 f32x4). BK=64, depth-2 two-register-set prefetch (R4-proven).
// XCD-aware work stealing: block reads its real XCD (HW_REG_XCC_ID) and pops
// work from that bucket's queue first (exactly-once via monotonic counters).
// Work item w -> (tileInBucket, ct, z):  ct fastest, then z, then tile.
// EPI=0: relu(acc+bias) -> split hi/lo bf16 to Aout (coalesced via LDS).
// EPI=1: acc (+bias iff z==0) -> fp32 scatter to outp + z*partStride.
template<int KH, int NN, int EPI, int NZ, int CT, int KB>
__global__ __launch_bounds__(256) void mfma_gemm(
    const short* __restrict__ A, const short* __restrict__ BT,
    const float* __restrict__ bias,
    short* __restrict__ Aout, float* __restrict__ outp, size_t partStride,
    const int* __restrict__ order,
    const int* __restrict__ meta,     // [8][2] tileBase, tileCnt
    int* __restrict__ ctr) {          // [8]
  constexpr int BK  = 64;
  constexpr int NCH = 3 * KH / BK;    // 12 or 24
  constexpr int CN  = NCH / NZ;
  constexpr int LDA = BK + 8;         // 72 shorts -> 2-way bank alias (free)
  __shared__ __align__(16) short smem[2 * 128 * LDA];   // As | Bs (36.9 KB)
  short* As = smem;
  short* Bs = smem + 128 * LDA;
  __shared__ int nodesS[128];
  __shared__ int workS;

  const int tid = threadIdx.x;
  if (tid == 0) {
    int xcd = __builtin_amdgcn_s_getreg((31u << 11) | 20) & 7;  // HW_REG_XCC_ID
    int q0 = (KB == 8) ? xcd : (xcd >> 1);
    int enc = -1;
    for (int t = 0; t < KB; ++t) {
      int q = q0 + t; if (q >= KB) q -= KB;
      int len = meta[2 * q + 1] * CT * NZ;
      if (len <= 0) continue;
      int i = atomicAdd(&ctr[q], 1);
      if (i < len) { enc = (q << 16) | i; break; }
    }
    workS = enc;
  }
  __syncthreads();
  const int enc = workS;
  if (enc < 0) return;
  const int kq = enc >> 16;
  const int w  = enc & 0xFFFF;
  const int tloc = w / (CT * NZ);
  const int rem  = w % (CT * NZ);
  const int ct = rem % CT;
  const int z  = rem / CT;
  const int row0 = (meta[2 * kq] + tloc) * TB;
  const int kfn = kq;                          // bucket index == fid
  const short* __restrict__ Bk = BT + (size_t)kfn * NN * (2 * KH);

  if (EPI == 1 && tid < 128) nodesS[tid] = order[row0 + tid];

  const int lane = tid & 63, wave = tid >> 6;
  const int l15 = lane & 15, oct = lane >> 4;
  const int wr = (wave >> 1) * 64;             // wave row base (0/64)
  const int wc = (wave & 1) * 64;              // wave col base (0/64)

  const int ar = tid >> 1;                     // staging: 128 rows/cols x 2 thr
  const int ag = (tid & 1) * 32;               // 32 shorts = 4 int4

  const int c0 = z * CN;

  f32x4 acc[4][4];
  #pragma unroll
  for (int i = 0; i < 4; ++i)
    #pragma unroll
    for (int j = 0; j < 4; ++j) acc[i][j] = (f32x4)0.f;

  int4 Ar[2][4], Br[2][4];
  auto loadA = [&](int set, int c) {
    int ko = c * BK, seg = ko / KH, wi = ko % KH;
    int pa = (seg == 1) ? KH + wi : wi;
    const int4* p = (const int4*)(A + (size_t)(row0 + ar) * (2 * KH) + pa + ag);
    #pragma unroll
    for (int q = 0; q < 4; ++q) Ar[set][q] = p[q];
  };
  auto loadB = [&](int set, int c) {
    int ko = c * BK, seg = ko / KH, wi = ko % KH;
    int pb = (seg == 2) ? KH + wi : wi;
    const int4* p = (const int4*)(Bk + (size_t)(ct * 128 + ar) * (2 * KH) + pb + ag);
    #pragma unroll
    for (int q = 0; q < 4; ++q) Br[set][q] = p[q];
  };
  auto storeLDS = [&](int set) {
    int4* da = (int4*)&As[ar * LDA + ag];
    #pragma unroll
    for (int q = 0; q < 4; ++q) da[q] = Ar[set][q];
    int4* db = (int4*)&Bs[ar * LDA + ag];
    #pragma unroll
    for (int q = 0; q < 4; ++q) db[q] = Br[set][q];
  };
  auto compute = [&]() {
    #pragma unroll
    for (int ss = 0; ss < 2; ++ss) {
      const int ko = ss * 32 + oct * 8;
      bf16x8 af[4], bf[4];
      #pragma unroll
      for (int rf = 0; rf < 4; ++rf)
        af[rf] = *(const bf16x8*)&As[(wr + rf * 16 + l15) * LDA + ko];
      #pragma unroll
      for (int cf = 0; cf < 4; ++cf)
        bf[cf] = *(const bf16x8*)&Bs[(wc + cf * 16 + l15) * LDA + ko];
      #pragma unroll
      for (int rf = 0; rf < 4; ++rf)
        #pragma unroll
        for (int cf = 0; cf < 4; ++cf)
          acc[rf][cf] = __builtin_amdgcn_mfma_f32_16x16x32_bf16(af[rf], bf[cf], acc[rf][cf], 0, 0, 0);
    }
  };

  loadA(0, c0); loadB(0, c0);
  if (CN > 1) { loadA(1, c0 + 1); loadB(1, c0 + 1); }
  for (int c = 0; c < CN; ++c) {
    const int s = c & 1;
    __syncthreads();
    storeLDS(s);
    __syncthreads();
    if (c + 2 < CN) { loadA(s, c0 + c + 2); loadB(s, c0 + c + 2); }
    compute();
  }

  // ---- Epilogue. C/D layout: col = l15, row = oct*4 + j (m89-verified).
  if (EPI == 0) {
    short* Ls = smem;                          // 128x128 shorts = 32 KB
    #pragma unroll
    for (int part = 0; part < 2; ++part) {
      __syncthreads();
      #pragma unroll
      for (int rf = 0; rf < 4; ++rf)
        #pragma unroll
        for (int cf = 0; cf < 4; ++cf) {
          int colL = wc + cf * 16 + l15;
          float bv = bias[kfn * NN + ct * 128 + colL];
          #pragma unroll
          for (int j = 0; j < 4; ++j) {
            int row = wr + rf * 16 + oct * 4 + j;
            float v = fmaxf(acc[rf][cf][j] + bv, 0.f);
            unsigned short hh = f2bf(v);
            unsigned short val = (part == 0) ? hh : f2bf(v - bf2f(hh));
            Ls[row * 128 + colL] = (short)val;
          }
        }
      __syncthreads();
      int row = tid >> 1, sg = (tid & 1) * 64;     // 64 shorts = 8 int4
      const int4* src = (const int4*)&Ls[row * 128 + sg];
      int4* dst = (int4*)&Aout[(size_t)(row0 + row) * (2 * NN) + part * NN + ct * 128 + sg];
      #pragma unroll
      for (int q = 0; q < 8; ++q) dst[q] = src[q];
    }
  } else {
    float* Lf = (float*)smem;                  // 128x64 fp32 = 32 KB per half
    #pragma unroll
    for (int h = 0; h < 2; ++h) {
      __syncthreads();
      if ((wave & 1) == h) {
        #pragma unroll
        for (int rf = 0; rf < 4; ++rf)
          #pragma unroll
          for (int cf = 0; cf < 4; ++cf) {
            int colL = cf * 16 + l15;
            float bv = (z == 0) ? bias[kfn * NN + h * 64 + colL] : 0.f;
            #pragma unroll
            for (int j = 0; j < 4; ++j) {
              int row = wr + rf * 16 + oct * 4 + j;
              Lf[row * 64 + colL] = acc[rf][cf][j] + bv;
            }
          }
      }
      __syncthreads();
      int row = tid >> 1, fo = (tid & 1) * 32;     // 32 floats = 8 float4
      int node = nodesS[row];
      if (node >= 0) {
        const float4* src = (const float4*)&Lf[row * 64 + fo];
        float4* dst = (float4*)&outp[(size_t)z * partStride + (size_t)node * 128 + h * 64 + fo];
        #pragma unroll
        for (int q = 0; q < 8; ++q) dst[q] = src[q];
      }
    }
  }
}

// ---------------------------------------------------------------------------
extern "C" void kernel_launch(void* const* d_in, const int* in_sizes, int n_in,
                              void* d_out, int out_size, void* d_ws, size_t ws_size,
                              hipStream_t stream) {
  const int*   leaf_ids  = (const int*)d_in[0];
  const int*   left_idx  = (const int*)d_in[1];
  const int*   right_idx = (const int*)d_in[2];
  const int*   nf_fid    = (const int*)d_in[3];
  const int*   gt_left   = (const int*)d_in[4];
  const int*   gt_right  = (const int*)d_in[5];
  const int*   lf_fid    = (const int*)d_in[6];
  const float* emb       = (const float*)d_in[7];
  const float* W1 = (const float*)d_in[8];
  const float* b1 = (const float*)d_in[9];
  const float* W2 = (const float*)d_in[10];
  const float* b2 = (const float*)d_in[11];
  const float* W3 = (const float*)d_in[12];
  const float* b3 = (const float*)d_in[13];
  const float* Wl1 = (const float*)d_in[14];
  const float* bl1 = (const float*)d_in[15];
  const float* Wl2 = (const float*)d_in[16];
  const float* bl2 = (const float*)d_in[17];
  float* out = (float*)d_out;

  const size_t SZ_H    = (size_t)M * D * 4;            // 4 MiB
  const size_t SZ_O    = (size_t)G * D * 4;            // 2 MiB
  const size_t SZ_XS   = (size_t)PADL * 512 * 2;
  const size_t SZ_A1   = (size_t)PADL * 1024 * 2;
  const size_t SZ_A2   = (size_t)PADL * 512 * 2;
  const size_t SZ_B1T  = (size_t)8 * 512 * 512 * 2;
  const size_t SZ_B2T  = (size_t)8 * 256 * 1024 * 2;
  const size_t SZ_B3T  = (size_t)8 * 128 * 512 * 2;
  const size_t SZ_BL1T = (size_t)4 * 512 * 512 * 2;
  const size_t SZ_BL2T = (size_t)4 * 128 * 1024 * 2;
  const size_t SZ_ORD  = (size_t)(5 * PADL + PADG) * 4;

  char* p = (char*)d_ws;
  float* hA  = (float*)p;  p += SZ_H;
  float* p0  = (float*)p;  p += 2 * SZ_H;   // level partial pair A (contiguous)
  float* q0  = (float*)p;  p += 2 * SZ_H;   // level partial pair B (contiguous)
  float* o0  = (float*)p;  p += 4 * SZ_O;   // logic2 partials x4 (contiguous)
  short* xsb = (short*)p;  p += SZ_XS;
  short* a1s = (short*)p;  p += SZ_A1;
  short* a2s = (short*)p;  p += SZ_A2;
  short* B1T  = (short*)p; p += SZ_B1T;
  short* B2T  = (short*)p; p += SZ_B2T;
  short* B3T  = (short*)p; p += SZ_B3T;
  short* BL1T = (short*)p; p += SZ_BL1T;
  short* BL2T = (short*)p; p += SZ_BL2T;
  int*   orders = (int*)p; p += SZ_ORD;
  int*   meta   = (int*)p; p += 6 * 16 * 4;
  int*   ctrs   = (int*)p;

  leaf_gather_kernel<<<(M * D) / 256, 256, 0, stream>>>(leaf_ids, emb, hA);
  bucket128_kernel<<<L + 1, 256, 0, stream>>>(nf_fid, lf_fid, orders, meta, ctrs);
  prep_kernel<<<9728, 256, 0, stream>>>(W1, W2, W3, Wl1, Wl2,
                                        B1T, B2T, B3T, BL1T, BL2T);

  const size_t HS = (size_t)M * D;   // floats between split-K partials
  float* in0 = hA; int sumin = 0;
  float* ou0 = q0;
  for (int l = 0; l < L; ++l) {
    const int* ord = orders + l * PADL;
    const int* mt = meta + l * 16;
    if (sumin == 0)
      gather_split_kernel<0><<<PADL / 32, 256, 0, stream>>>(
          in0, HS, ord, left_idx + l * M, right_idx + l * M, xsb);
    else
      gather_split_kernel<1><<<PADL / 32, 256, 0, stream>>>(
          in0, HS, ord, left_idx + l * M, right_idx + l * M, xsb);
    // GEMM1: K'=768, N=512, CT=4 -> 288 blocks
    mfma_gemm<256, 512, 0, 1, 4, 8><<<(PADL / TB) * 4, 256, 0, stream>>>(
        xsb, B1T, b1, a1s, nullptr, 0, ord, mt, ctrs + (3 * l + 0) * 8);
    // GEMM2: K'=1536, N=256, CT=2 -> 144 blocks
    mfma_gemm<512, 256, 0, 1, 2, 8><<<(PADL / TB) * 2, 256, 0, stream>>>(
        a1s, B2T, b2, a2s, nullptr, 0, ord, mt, ctrs + (3 * l + 1) * 8);
    // GEMM3: K'=768, N=128, CT=1, split-K z=2 -> 144 blocks
    mfma_gemm<256, 128, 1, 2, 1, 8><<<(PADL / TB) * 2, 256, 0, stream>>>(
        a2s, B3T, b3, nullptr, ou0, HS, ord, mt, ctrs + (3 * l + 2) * 8);
    in0 = ou0; sumin = 1;
    ou0 = (ou0 == q0) ? p0 : q0;
  }
  const int* ordG = orders + L * PADL;
  const int* mtG = meta + L * 16;
  gather_split_kernel<1><<<PADG / 32, 256, 0, stream>>>(
      in0, HS, ordG, gt_left, gt_right, xsb);
  // Logic GEMM1: K'=768, N=512, CT=4, KB=4 -> 144 blocks
  mfma_gemm<256, 512, 0, 1, 4, 4><<<(PADG / TB) * 4, 256, 0, stream>>>(
      xsb, BL1T, bl1, a1s, nullptr, 0, ordG, mtG, ctrs + 15 * 8);
  // Logic GEMM2: K'=1536, N=128, CT=1, split-K z=4, KB=4 -> 144 blocks
  mfma_gemm<512, 128, 1, 4, 1, 4><<<(PADG / TB) * 4, 256, 0, stream>>>(
      a1s, BL2T, bl2, nullptr, o0, (size_t)G * D, ordG, mtG, ctrs + 16 * 8);
  add_out4_kernel<<<(G * D) / 256, 256, 0, stream>>>(o0, (size_t)G * D, out);
}